// Round 7
// baseline (451.567 us; speedup 1.0000x reference)
//
#include <hip/hip_runtime.h>

// Problem constants
#define S_  2048
#define D_  1024
#define H_  16
#define B_  4

typedef __attribute__((ext_vector_type(8))) short short8;
typedef __attribute__((ext_vector_type(4))) float f32x4;

__device__ __forceinline__ unsigned short f2bf(float f) {
  unsigned int u = __float_as_uint(f);
  u += 0x7fffu + ((u >> 16) & 1u);      // round-to-nearest-even
  return (unsigned short)(u >> 16);
}
__device__ __forceinline__ unsigned int pack2(float a, float b) {
  return (unsigned int)f2bf(a) | ((unsigned int)f2bf(b) << 16);
}

// Barrier that drains ONLY LDS ops; global loads/stores stay in flight.
// (__syncthreads would emit s_waitcnt vmcnt(0) -> store-latency exposed.)
__device__ __forceinline__ void bar_lgkm() {
  asm volatile("s_waitcnt lgkmcnt(0)" ::: "memory");
  __builtin_amdgcn_sched_barrier(0);     // rule #18: pin ops after the wait
  __builtin_amdgcn_s_barrier();
}

// 0.125 (1/sqrt(DK)) * log2(e): use exp2 (native v_exp_f32)
#define SCL 0.18033688011112042f

// ---------------------------------------------------------------------------
// x (B,S,D) f32 -> xh (B,H,S,64) bf16 head-major (256 KB contiguous per bh).
// ---------------------------------------------------------------------------
__global__ __launch_bounds__(256) void xcvt(const float* __restrict__ x,
                                            unsigned short* __restrict__ xh) {
  const int n = blockIdx.x;
  const int bh = n >> 5, chunk = n & 31;
  const int b = bh >> 4, h = bh & 15;
  const int r = threadIdx.x >> 2, cg = threadIdx.x & 3;
  const int srow = chunk * 64 + r;
  const float* src = x + ((size_t)b * S_ + srow) * D_ + h * 64 + cg * 16;
  float4 v0 = ((const float4*)src)[0];
  float4 v1 = ((const float4*)src)[1];
  float4 v2 = ((const float4*)src)[2];
  float4 v3 = ((const float4*)src)[3];
  uint4 w0, w1;
  w0.x = pack2(v0.x, v0.y); w0.y = pack2(v0.z, v0.w);
  w0.z = pack2(v1.x, v1.y); w0.w = pack2(v1.z, v1.w);
  w1.x = pack2(v2.x, v2.y); w1.y = pack2(v2.z, v2.w);
  w1.z = pack2(v3.x, v3.y); w1.w = pack2(v3.z, v3.w);
  unsigned short* dst = xh + ((size_t)bh * S_ + srow) * 64 + cg * 16;
  *(uint4*)dst = w0;
  *(uint4*)(dst + 8) = w1;
}

// ---------------------------------------------------------------------------
// Two-pass fused attention, counted-wait pipeline.
// Block = 256 thr (4 waves x 16 q-rows) = 64-row q-tile, full S keys.
// Per chunk: prefetch(c+1) global->regs at top (latency hides under MFMA+exp),
// commit regs->LDS (XOR-swizzled, double-buffered) after compute, barrier
// drains lgkm only -- nontemporal attn stores pipeline across all 16 chunks.
// Pass A: row sums. Pass B: write attn + deterministic column partials.
// grid = 2048, XCD-swizzled (8 bh-slices per XCD -> K stays L2-resident).
// ---------------------------------------------------------------------------
__global__ __launch_bounds__(256, 4) void attn_fused(
    const unsigned short* __restrict__ xh, const int* __restrict__ sl32,
    float* __restrict__ attn, float* __restrict__ cpart)
{
  __shared__ __align__(16) unsigned short kbuf[2][128 * 64]; // 2 x 16 KB
  __shared__ float colbuf[2][4][128];                        // 4 KB

  const int n    = blockIdx.x;
  const int xcd  = n & 7;
  const int slot = n >> 3;                 // 0..255 per XCD
  const int bh   = (slot >> 5) * 8 + xcd;  // 8 bh-slices per XCD
  const int qt   = slot & 31;              // 32 q-tiles of 64 rows
  const int b    = bh >> 4;
  const int tid  = threadIdx.x;
  const int wv   = tid >> 6;
  const int lane = tid & 63;
  const int lo   = lane & 15;
  const int g    = lane >> 4;

  // seq_lens dtype auto-detect (values >= 1024 -> int64 layout has word1==0)
  const bool is64 = (sl32[1] == 0);
  const int seqlen = is64 ? sl32[2 * b] : sl32[b];

  const unsigned short* xk = xh + (size_t)bh * S_ * 64;
  const int qbase = qt * 64 + wv * 16;

  // Q fragment (A-frag): row = lo, k = g*8 + i (+32)
  short8 aq0 = *(const short8*)(xk + (size_t)(qbase + lo) * 64 + g * 8);
  short8 aq1 = *(const short8*)(xk + (size_t)(qbase + lo) * 64 + g * 8 + 32);

  // Staging: thread t -> key row sk = t>>1, 64B half shf = t&1 (4 x uint4).
  const int sk = tid >> 1, shf = tid & 1;
  uint4 streg[4];
  auto prefetch = [&](int c) {
    const uint4* src = (const uint4*)(xk + (size_t)(c * 128 + sk) * 64) + shf * 4;
#pragma unroll
    for (int q = 0; q < 4; ++q) streg[q] = src[q];
  };
  auto commit = [&](unsigned short* dst) {
    uint4* d = (uint4*)&dst[sk * 64];
    const int sw = sk & 7;
#pragma unroll
    for (int q = 0; q < 4; ++q) d[(shf * 4 + q) ^ sw] = streg[q];
  };

  auto qk_tile = [&](const unsigned short* kb, int kt) -> f32x4 {
    const int key = kt * 16 + lo;
    const int cs = g ^ (key & 7);
    short8 b0 = *(const short8*)&kb[key * 64 + cs * 8];
    short8 b1 = *(const short8*)&kb[key * 64 + (cs ^ 4) * 8];
    f32x4 acc = {0.f, 0.f, 0.f, 0.f};
    acc = __builtin_amdgcn_mfma_f32_16x16x32_bf16(aq0, b0, acc, 0, 0, 0);
    acc = __builtin_amdgcn_mfma_f32_16x16x32_bf16(aq1, b1, acc, 0, 0, 0);
    return acc;
  };

  // ---------------- Pass A: row sums ----------------
  float rsum[4] = {0.f, 0.f, 0.f, 0.f};
  prefetch(0);
  commit(kbuf[0]);
  bar_lgkm();
  for (int c = 0; c < 16; ++c) {
    if (c < 15) prefetch(c + 1);           // issue loads; consumed at commit
    const unsigned short* kb = kbuf[c & 1];
#pragma unroll
    for (int kt = 0; kt < 8; ++kt) {
      f32x4 acc = qk_tile(kb, kt);
      const bool valid = (c * 128 + kt * 16 + lo) < seqlen;
#pragma unroll
      for (int r = 0; r < 4; ++r)
        rsum[r] += valid ? exp2f(acc[r] * SCL) : 0.f;
    }
    if (c < 15) commit(kbuf[(c + 1) & 1]);
    bar_lgkm();
  }
#pragma unroll
  for (int r = 0; r < 4; ++r) {
    float v = rsum[r];
    v += __shfl_xor(v, 1);
    v += __shfl_xor(v, 2);
    v += __shfl_xor(v, 4);
    v += __shfl_xor(v, 8);
    rsum[r] = 1.0f / v;                 // 1/l for rows g*4+r
  }

  // ---------------- Pass B: write attn + column partials ----------------
  float* pr = attn + (size_t)bh * S_ * S_ + (size_t)(qbase + g * 4) * S_ + lo;
  float* cp = cpart + ((size_t)bh * 32 + qt) * 2048;
  prefetch(0);
  commit(kbuf[0]);
  bar_lgkm();
  for (int c = 0; c < 16; ++c) {
    if (c < 15) prefetch(c + 1);
    const unsigned short* kb = kbuf[c & 1];
#pragma unroll
    for (int kt = 0; kt < 8; ++kt) {
      f32x4 acc = qk_tile(kb, kt);
      const bool valid = (c * 128 + kt * 16 + lo) < seqlen;
      float a0 = valid ? exp2f(acc[0] * SCL) * rsum[0] : 0.f;
      float a1 = valid ? exp2f(acc[1] * SCL) * rsum[1] : 0.f;
      float a2 = valid ? exp2f(acc[2] * SCL) * rsum[2] : 0.f;
      float a3 = valid ? exp2f(acc[3] * SCL) * rsum[3] : 0.f;
      const int off = c * 128 + kt * 16;
      __builtin_nontemporal_store(a0, pr + off);
      __builtin_nontemporal_store(a1, pr + (size_t)1 * S_ + off);
      __builtin_nontemporal_store(a2, pr + (size_t)2 * S_ + off);
      __builtin_nontemporal_store(a3, pr + (size_t)3 * S_ + off);
      float cv = a0 + a1 + a2 + a3;
      cv += __shfl_xor(cv, 16);
      cv += __shfl_xor(cv, 32);         // sum over the wave's 16 rows
      if (lane < 16) colbuf[c & 1][wv][kt * 16 + lo] = cv;
    }
    if (c < 15) commit(kbuf[(c + 1) & 1]);
    bar_lgkm();
    // colbuf[c&1] complete for all 4 waves; next iteration uses the other buf
    if (tid < 128)
      cp[c * 128 + tid] = colbuf[c & 1][0][tid] + colbuf[c & 1][1][tid] +
                          colbuf[c & 1][2][tid] + colbuf[c & 1][3][tid];
  }
}

// c[bh][k] = sum over 32 q-tiles of cpart
__global__ __launch_bounds__(256) void creduce(const float* __restrict__ cpart,
                                               float* __restrict__ c) {
  const int i = blockIdx.x * 256 + threadIdx.x;   // 64*2048 total
  const int bh = i >> 11, k = i & 2047;
  float s = 0.f;
#pragma unroll 8
  for (int qt = 0; qt < 32; ++qt) s += cpart[((size_t)bh * 32 + qt) * 2048 + k];
  c[i] = s;
}

// csump[oct][bh][d] = sum over oct's 256 keys of c[bh][k] * xh[bh][k][d]
__global__ __launch_bounds__(256) void csum_k(const float* __restrict__ c,
                                              const unsigned short* __restrict__ xh,
                                              float* __restrict__ csump) {
  __shared__ float part[4][64];
  const int bh = blockIdx.x >> 3, oct = blockIdx.x & 7;
  const int seg = threadIdx.x >> 6, d = threadIdx.x & 63;
  const float* cb = c + bh * 2048;
  const unsigned short* xb = xh + (size_t)bh * S_ * 64 + d;
  const int k0 = oct * 256 + seg * 64;
  float acc = 0.f;
#pragma unroll 4
  for (int k = k0; k < k0 + 64; ++k) {
    float xv = __uint_as_float((unsigned int)xb[(size_t)k * 64] << 16);
    acc += cb[k] * xv;
  }
  part[seg][d] = acc;
  __syncthreads();
  if (threadIdx.x < 64)
    csump[((size_t)oct * 64 + bh) * 64 + d] =
        part[0][d] + part[1][d] + part[2][d] + part[3][d];
}

// out0[b][d] = sum_e csum[b][e] * W[d][e] + S * bias[d], csum = sum of octants
__global__ __launch_bounds__(256) void proj_k(const float* __restrict__ csump,
                                              const float* __restrict__ W,
                                              const float* __restrict__ bias,
                                              float* __restrict__ out0) {
  const int idx = blockIdx.x * 4 + (threadIdx.x >> 6); // (b,d) pair per wave
  const int b = idx >> 10, d = idx & 1023;
  const int lane = threadIdx.x & 63;
  const float* wr = W + (size_t)d * D_;
  float acc = 0.f;
#pragma unroll
  for (int e = 0; e < 16; ++e) {
    const int ei = lane + e * 64;            // e index within D
    const int bhh = b * 16 + (ei >> 6);      // bh of this e
    const int dd = ei & 63;
    float cv = 0.f;
#pragma unroll
    for (int oct = 0; oct < 8; ++oct)
      cv += csump[((size_t)oct * 64 + bhh) * 64 + dd];
    acc += cv * wr[ei];
  }
  acc += __shfl_xor(acc, 32);
  acc += __shfl_xor(acc, 16);
  acc += __shfl_xor(acc, 8);
  acc += __shfl_xor(acc, 4);
  acc += __shfl_xor(acc, 2);
  acc += __shfl_xor(acc, 1);
  if (lane == 0) out0[idx] = acc + 2048.0f * bias[d];
}

extern "C" void kernel_launch(void* const* d_in, const int* in_sizes, int n_in,
                              void* d_out, int out_size, void* d_ws, size_t ws_size,
                              hipStream_t stream) {
  const float* x    = (const float*)d_in[0];
  const int*   sl   = (const int*)d_in[1];
  const float* W    = (const float*)d_in[2];
  const float* bias = (const float*)d_in[3];

  float* out0 = (float*)d_out;
  float* attn = out0 + B_ * D_;

  float* cpart = (float*)d_ws;                       // 64*32*2048 f32 = 16 MB
  float* c     = cpart + (size_t)64 * 32 * 2048;     // 64*2048 f32 = 512 KB
  float* csump = c + 64 * 2048;                      // 8*64*64 f32 = 128 KB
  unsigned short* xh = (unsigned short*)(csump + 8 * 64 * 64); // bf16, 16 MB

  hipLaunchKernelGGL(xcvt,       dim3(2048), dim3(256), 0, stream, x, xh);
  hipLaunchKernelGGL(attn_fused, dim3(2048), dim3(256), 0, stream, xh, sl, attn, cpart);
  hipLaunchKernelGGL(creduce,    dim3(512),  dim3(256), 0, stream, cpart, c);
  hipLaunchKernelGGL(csum_k,     dim3(512),  dim3(256), 0, stream, c, xh, csump);
  hipLaunchKernelGGL(proj_k,     dim3(1024), dim3(256), 0, stream, csump, W, bias, out0);
}